// Round 15
// baseline (295.150 us; speedup 1.0000x reference)
//
#include <hip/hip_runtime.h>

#define LLEN 8192
#define CG 16
#define NG 512    // b(16) * GROUPS(32)
#define NBLK 512  // 64 blocks/XCD = 8 teams x 8 members
#define THREADS 512

typedef float f32x4 __attribute__((ext_vector_type(4)));
typedef float f32x2 __attribute__((ext_vector_type(2)));

__global__ __launch_bounds__(THREADS) void zero_flags(int* __restrict__ flags) {
    flags[threadIdx.x] = 0;     // NG == 512 == THREADS
}

// Pipelined team-cooperative persistent kernel. Team = 8 blocks on one XCD
// (blockIdx%8 = XCD). Each team processes 8 groups with a 1-deep pipeline:
//   iter t: [phase1(t+1): HBM read + partial sums -> wsS, flag++]
//           [spin flag(t)==8  -- satisfied one iteration ago -> ~free]
//           [prep(t): softmax -> taps V]
//           [phase2(t): re-read x (L2-warm), gate, NT-store out]
// so HBM-read(t+1), L2-read(t) and NT-write(t) overlap every iteration.
extern "C" __global__ __launch_bounds__(THREADS)
void fused_team(const float* __restrict__ x,  const float* __restrict__ w1,
                const float* __restrict__ b1, const float* __restrict__ w3,
                const float* __restrict__ b3, float* __restrict__ out,
                float* __restrict__ wsS, int* __restrict__ flags) {
    __shared__ float V[49];             // v0[0:16) v1[16:32) v2[32:48) cb

    const int b    = blockIdx.x;
    const int wave = threadIdx.x >> 6;  // 0..7
    const int lane = threadIdx.x & 63;
    const int xcd  = b & 7;
    const int slot = b >> 3;            // 0..63 within XCD
    const int team = xcd * 8 + (slot >> 3);   // 0..63
    const int m    = slot & 7;          // member 0..7

    // phase 1: member m partial-sums rows (wave, wave+8) over cols [1024m, +1024)
    auto p1 = [&](int g) {
        const size_t rowbase = (size_t)g * CG * LLEN;
        const float* r0 = x + rowbase + (size_t)wave * LLEN + 1024 * m;
        const float* r1 = r0 + (size_t)8 * LLEN;
        float s0 = 0.f, s1 = 0.f;
        #pragma unroll
        for (int k = 0; k < 4; ++k) {
            f32x4 v0 = *reinterpret_cast<const f32x4*>(r0 + 256 * k + 4 * lane);
            f32x4 v1 = *reinterpret_cast<const f32x4*>(r1 + 256 * k + 4 * lane);
            s0 += (v0.x + v0.y) + (v0.z + v0.w);
            s1 += (v1.x + v1.y) + (v1.z + v1.w);
        }
        #pragma unroll
        for (int off = 32; off; off >>= 1) {
            s0 += __shfl_xor(s0, off, 64);
            s1 += __shfl_xor(s1, off, 64);
        }
        if (lane == 0) {
            __hip_atomic_store(&wsS[g * 128 + m * 16 + wave], s0,
                               __ATOMIC_RELAXED, __HIP_MEMORY_SCOPE_AGENT);
            __hip_atomic_store(&wsS[g * 128 + m * 16 + wave + 8], s1,
                               __ATOMIC_RELAXED, __HIP_MEMORY_SCOPE_AGENT);
        }
    };

    // prologue: stage group 0
    p1(team * 8);
    __syncthreads();                    // stores drained before flag
    if (threadIdx.x == 0)
        __hip_atomic_fetch_add(&flags[team * 8], 1, __ATOMIC_ACQ_REL,
                               __HIP_MEMORY_SCOPE_AGENT);

    for (int t = 0; t < 8; ++t) {
        const int g = team * 8 + t;
        const size_t rowbase = (size_t)g * CG * LLEN;

        // ---- stage next group (overlaps with this group's consume) ----
        if (t < 7) {
            p1(g + 1);
            __syncthreads();
            if (threadIdx.x == 0)
                __hip_atomic_fetch_add(&flags[g + 1], 1, __ATOMIC_ACQ_REL,
                                       __HIP_MEMORY_SCOPE_AGENT);
        }
        // ---- rendezvous for this group (satisfied last iteration) ----
        if (threadIdx.x == 0) {
            while (__hip_atomic_load(&flags[g], __ATOMIC_ACQUIRE,
                                     __HIP_MEMORY_SCOPE_AGENT) < 8)
                __builtin_amdgcn_s_sleep(1);
        }
        __syncthreads();   // also orders phase2(t-1)'s V reads before prep(t)

        // ---- prep: softmax -> collapsed taps (wave 0) ----
        if (wave == 0) {
            const int i = lane & 15;
            float S = 0.f;
            #pragma unroll
            for (int mm = 0; mm < 8; ++mm)
                S += __hip_atomic_load(&wsS[g * 128 + mm * 16 + i],
                                       __ATOMIC_RELAXED, __HIP_MEMORY_SCOPE_AGENT);
            float Fv = x[rowbase + (size_t)i * LLEN];
            float Lv = x[rowbase + (size_t)i * LLEN + (LLEN - 1)];
            const float invL = 1.0f / (float)LLEN;
            float s1a = 0.f, s2a = 0.f;
            #pragma unroll
            for (int k = 0; k < CG; ++k) {
                float Sk = __shfl(S,  k, 16);
                float Fk = __shfl(Fv, k, 16);
                float Lk = __shfl(Lv, k, 16);
                s1a += w1[i * CG + k] * Sk;
                const float* wp = &w3[(i * CG + k) * 3];
                s2a += wp[0] * (Sk - Lk) + wp[1] * Sk + wp[2] * (Sk - Fk);
            }
            float m1 = s1a * invL + b1[i];
            float m2 = s2a * invL + b3[i];

            float mx1 = m1, mx2 = m2;
            #pragma unroll
            for (int off = 8; off; off >>= 1) {
                mx1 = fmaxf(mx1, __shfl_xor(mx1, off, 16));
                mx2 = fmaxf(mx2, __shfl_xor(mx2, off, 16));
            }
            float e1 = __expf(m1 - mx1), e2 = __expf(m2 - mx2);
            float d1 = e1, d2 = e2;
            #pragma unroll
            for (int off = 8; off; off >>= 1) {
                d1 += __shfl_xor(d1, off, 16);
                d2 += __shfl_xor(d2, off, 16);
            }
            float a1 = e1 / d1, a2 = e2 / d2;

            float cb = a1 * b3[i] + a2 * b1[i];
            #pragma unroll
            for (int off = 8; off; off >>= 1) cb += __shfl_xor(cb, off, 16);

            float v0 = 0.f, v1v = 0.f, v2 = 0.f;
            #pragma unroll
            for (int k = 0; k < CG; ++k) {
                float a1k = __shfl(a1, k, 16);
                float a2k = __shfl(a2, k, 16);
                const float* wp = &w3[(k * CG + i) * 3];
                v0  += a1k * wp[0];
                v1v += a1k * wp[1] + a2k * w1[k * CG + i];
                v2  += a1k * wp[2];
            }
            if (lane < 16) {
                V[i]      = v0;
                V[16 + i] = v1v;
                V[32 + i] = v2;
                if (lane == 0) V[48] = cb;
            }
        }
        __syncthreads();

        // ---- phase 2: wave owns 128 cols [c0, c0+128), lane owns 2 cols ----
        const int c0 = 1024 * m + 128 * wave;
        const int cl = c0 + 2 * lane;
        float wlo = 0.f, whi = 0.f;
        f32x2 xv[CG];
        #pragma unroll
        for (int i = 0; i < CG; ++i) {
            size_t rb = rowbase + (size_t)i * LLEN;
            f32x2 v = *reinterpret_cast<const f32x2*>(x + rb + cl);
            xv[i] = v;
            float le = 0.f, re = 0.f;
            if (c0 > 0)           le = x[rb + c0 - 1];     // uniform -> scalar, L2 hit
            if (c0 + 128 < LLEN)  re = x[rb + c0 + 128];
            float fl = __shfl_up(v.y, 1, 64);
            if (lane == 0)  fl = le;
            float fr = __shfl_down(v.x, 1, 64);
            if (lane == 63) fr = re;
            const float a0 = V[i], a1 = V[16 + i], a2 = V[32 + i];
            wlo += a0 * fl  + a1 * v.x + a2 * v.y;
            whi += a0 * v.x + a1 * v.y + a2 * fr;
        }
        const float cbv = V[48];
        const float qlo = 1.f / (1.f + __expf(-(wlo + cbv)));
        const float qhi = 1.f / (1.f + __expf(-(whi + cbv)));
        #pragma unroll
        for (int i = 0; i < CG; ++i) {
            size_t rb = rowbase + (size_t)i * LLEN + cl;
            f32x2 o2 = { xv[i].x * qlo, xv[i].y * qhi };
            __builtin_nontemporal_store(o2, reinterpret_cast<f32x2*>(out + rb));
        }
        // no trailing barrier: next iteration's first __syncthreads orders
        // this phase2's V reads before prep(t+1) rewrites V.
    }
}

extern "C" void kernel_launch(void* const* d_in, const int* in_sizes, int n_in,
                              void* d_out, int out_size, void* d_ws, size_t ws_size,
                              hipStream_t stream) {
    const float* x  = (const float*)d_in[0];
    const float* w1 = (const float*)d_in[1];
    const float* b1 = (const float*)d_in[2];
    const float* w3 = (const float*)d_in[3];
    const float* b3 = (const float*)d_in[4];
    float* out = (float*)d_out;

    int*   flags = (int*)d_ws;                          // 512 ints
    float* wsS   = (float*)((char*)d_ws + 2048);        // 512 * 128 floats

    zero_flags<<<1, THREADS, 0, stream>>>(flags);
    fused_team<<<NBLK, THREADS, 0, stream>>>(x, w1, b1, w3, b3, out, wsS, flags);
}

// Round 16
// 129.374 us; speedup vs baseline: 2.2814x; 2.2814x over previous
//
#include <hip/hip_runtime.h>

#define LLEN 8192
#define CG 16
#define NG 512   // b(16) * GROUPS(32)

typedef float f32x4 __attribute__((ext_vector_type(4)));

// ---------------- Pass 1: row sums + per-group prep, fused. One block per group. ----
// 1024 threads = 16 waves; wave w sums row w. Then wave 0 computes softmax weights
// and the collapsed 3-tap vectors v0,v1,v2 and scalar bias c, writes vw[g*64..].
__global__ __launch_bounds__(1024) void sumprep_kernel(const float* __restrict__ x,
                                                       const float* __restrict__ w1,
                                                       const float* __restrict__ b1,
                                                       const float* __restrict__ w3,
                                                       const float* __restrict__ b3,
                                                       float* __restrict__ vw) {
    int g    = blockIdx.x;              // 0..511
    int wave = threadIdx.x >> 6;        // 0..15  == row within group
    int lane = threadIdx.x & 63;
    __shared__ float S_lds[CG], F_lds[CG], L_lds[CG];

    const float4* xr = reinterpret_cast<const float4*>(x + (size_t)(g * CG + wave) * LLEN);
    float s = 0.f;
    #pragma unroll
    for (int k = 0; k < 32; ++k) {
        float4 v = xr[k * 64 + lane];
        s += (v.x + v.y) + (v.z + v.w);
    }
    #pragma unroll
    for (int off = 32; off; off >>= 1)
        s += __shfl_down(s, off, 64);
    if (lane == 0) S_lds[wave] = s;
    if (threadIdx.x < CG) {
        size_t rb = (size_t)(g * CG + threadIdx.x) * LLEN;
        F_lds[threadIdx.x] = x[rb];
        L_lds[threadIdx.x] = x[rb + (LLEN - 1)];
    }
    __syncthreads();

    if (wave == 0) {
        int i = lane & 15;              // channel index (lanes 16..63 duplicate)
        const float invL = 1.0f / (float)LLEN;
        float s1 = 0.f, s2 = 0.f;
        #pragma unroll
        for (int k = 0; k < CG; ++k) {
            float Sk = S_lds[k], Fk = F_lds[k], Lk = L_lds[k];
            s1 += w1[i * CG + k] * Sk;
            const float* w = &w3[(i * CG + k) * 3];
            s2 += w[0] * (Sk - Lk) + w[1] * Sk + w[2] * (Sk - Fk);
        }
        float m1 = s1 * invL + b1[i];
        float m2 = s2 * invL + b3[i];

        // softmax across the 16-lane group (both heads)
        float mx1 = m1, mx2 = m2;
        #pragma unroll
        for (int off = 8; off; off >>= 1) {
            mx1 = fmaxf(mx1, __shfl_xor(mx1, off, 16));
            mx2 = fmaxf(mx2, __shfl_xor(mx2, off, 16));
        }
        float e1 = __expf(m1 - mx1), e2 = __expf(m2 - mx2);
        float d1 = e1, d2 = e2;
        #pragma unroll
        for (int off = 8; off; off >>= 1) {
            d1 += __shfl_xor(d1, off, 16);
            d2 += __shfl_xor(d2, off, 16);
        }
        float a1 = e1 / d1, a2 = e2 / d2;

        float cb = a1 * b3[i] + a2 * b1[i];
        #pragma unroll
        for (int off = 8; off; off >>= 1) cb += __shfl_xor(cb, off, 16);

        float v0 = 0.f, v1v = 0.f, v2 = 0.f;
        #pragma unroll
        for (int k = 0; k < CG; ++k) {
            float a1k = __shfl(a1, k, 16);
            float a2k = __shfl(a2, k, 16);
            const float* w = &w3[(k * CG + i) * 3];
            v0  += a1k * w[0];
            v1v += a1k * w[1] + a2k * w1[k * CG + i];
            v2  += a1k * w[2];
        }
        if (lane < 16) {
            float* outv = &vw[g * 64];
            outv[i]      = v0;
            outv[16 + i] = v1v;
            outv[32 + i] = v2;
            if (lane == 0) outv[48] = cb;
        }
    }
}

// ---------------- Pass 2: weights -> sigmoid gate -> output ----------------
// One wave per (group, 256-column chunk), REVERSE traversal (freshest L3 lines
// first after sumprep's forward stream), NT stores (out doesn't allocate in L3,
// so x's resident lines survive the write stream).
__global__ __launch_bounds__(256) void apply_kernel(const float* __restrict__ x,
                                                    const float* __restrict__ vw,
                                                    float* __restrict__ out) {
    int wavg = (blockIdx.x * 256 + threadIdx.x) >> 6;   // 0..16383
    int lane = threadIdx.x & 63;
    int g  = NG - 1 - (wavg >> 5);          // 511..0
    int c0 = (31 - (wavg & 31)) * 256;      // reverse chunks within group too
    const float* vp = &vw[g * 64];

    const float cb = vp[48];
    float w0 = cb, w1a = cb, w2a = cb, w3a = cb;
    float4 xv[CG];
    #pragma unroll
    for (int i = 0; i < CG; ++i) {
        size_t rb = ((size_t)(g * CG + i)) * LLEN + c0;
        float4 v = *reinterpret_cast<const float4*>(x + rb + 4 * lane);
        xv[i] = v;
        float le = 0.f, re = 0.f;
        if (c0 > 0)            le = x[rb - 1];          // uniform addr -> scalar load
        if (c0 + 256 < LLEN)   re = x[rb + 256];
        float fl = __shfl_up(v.w, 1, 64);
        if (lane == 0)  fl = le;
        float fr = __shfl_down(v.x, 1, 64);
        if (lane == 63) fr = re;
        const float a0 = vp[i], a1 = vp[16 + i], a2 = vp[32 + i];
        w0  += a0 * fl  + a1 * v.x + a2 * v.y;
        w1a += a0 * v.x + a1 * v.y + a2 * v.z;
        w2a += a0 * v.y + a1 * v.z + a2 * v.w;
        w3a += a0 * v.z + a1 * v.w + a2 * fr;
    }
    const float s0 = 1.f / (1.f + __expf(-w0));
    const float s1 = 1.f / (1.f + __expf(-w1a));
    const float s2 = 1.f / (1.f + __expf(-w2a));
    const float s3 = 1.f / (1.f + __expf(-w3a));
    #pragma unroll
    for (int i = 0; i < CG; ++i) {
        size_t rb = ((size_t)(g * CG + i)) * LLEN + c0 + 4 * lane;
        float4 v = xv[i];
        f32x4 o4 = { v.x * s0, v.y * s1, v.z * s2, v.w * s3 };
        __builtin_nontemporal_store(o4, reinterpret_cast<f32x4*>(out + rb));
    }
}

extern "C" void kernel_launch(void* const* d_in, const int* in_sizes, int n_in,
                              void* d_out, int out_size, void* d_ws, size_t ws_size,
                              hipStream_t stream) {
    const float* x  = (const float*)d_in[0];
    const float* w1 = (const float*)d_in[1];
    const float* b1 = (const float*)d_in[2];
    const float* w3 = (const float*)d_in[3];
    const float* b3 = (const float*)d_in[4];
    float* out = (float*)d_out;
    float* vw  = (float*)d_ws;              // 512 * 64 floats

    // Pass 1: one block per group, 16 waves (one per row), prep fused in-block.
    sumprep_kernel<<<NG, 1024, 0, stream>>>(x, w1, b1, w3, b3, vw);
    // Pass 2: 512 groups * 32 chunks = 16384 waves / 4 per block, reverse order, NT.
    apply_kernel<<<4096, 256, 0, stream>>>(x, vw, out);
}